// Round 11
// baseline (279.744 us; speedup 1.0000x reference)
//
#include <hip/hip_runtime.h>

#define NROW 16384
#define DDIM 128
#define NITER (NROW / 64)

typedef _Float16 f16x8 __attribute__((ext_vector_type(8)));
typedef __fp16 fp16x2 __attribute__((ext_vector_type(2)));
typedef float f32x4 __attribute__((ext_vector_type(4)));

__device__ __forceinline__ unsigned short f2h(float x) {
  union { _Float16 f; unsigned short u; } cvt;
  cvt.f = (_Float16)x;  // RNE
  return cvt.u;
}

__device__ __forceinline__ unsigned pkrtz(float a, float b) {
  union { fp16x2 h; unsigned u; } cvt;
  cvt.h = __builtin_amdgcn_cvt_pkrtz(a, b);  // v_cvt_pkrtz_f16_f32
  return cvt.u;
}

__device__ __forceinline__ void gll16(const void* g, void* l) {
  __builtin_amdgcn_global_load_lds(
      (const __attribute__((address_space(1))) unsigned int*)g,
      (__attribute__((address_space(3))) unsigned int*)l, 16, 0, 0);
}

// ---------------- prep: ht[d][i] = fp16(h[i][d]) ----------------
__global__ __launch_bounds__(256) void prep_ht(const float* __restrict__ h,
                                               unsigned short* __restrict__ ht) {
  __shared__ unsigned short tile[DDIM][65];  // 65: 2-way-free transpose
  const int t = threadIdx.x;
  const int i0 = blockIdx.x * 64;
#pragma unroll
  for (int rep = 0; rep < 8; ++rep) {
    int idx = rep * 256 + t;          // 0..2047 float4s of a 64x128 tile
    int r = idx >> 5, c4 = idx & 31;
    const float4 v = *(const float4*)(h + (size_t)(i0 + r) * DDIM + c4 * 4);
    int c = c4 * 4;
    tile[c + 0][r] = f2h(v.x);
    tile[c + 1][r] = f2h(v.y);
    tile[c + 2][r] = f2h(v.z);
    tile[c + 3][r] = f2h(v.w);
  }
  __syncthreads();
#pragma unroll
  for (int rep = 0; rep < 4; ++rep) {
    int idx = rep * 256 + t;          // 0..1023 groups of 8
    int d = idx >> 3, io = (idx & 7) * 8;
    uint4 o;
    o.x = (unsigned)tile[d][io + 0] | ((unsigned)tile[d][io + 1] << 16);
    o.y = (unsigned)tile[d][io + 2] | ((unsigned)tile[d][io + 3] << 16);
    o.z = (unsigned)tile[d][io + 4] | ((unsigned)tile[d][io + 5] << 16);
    o.w = (unsigned)tile[d][io + 6] | ((unsigned)tile[d][io + 7] << 16);
    *(uint4*)(ht + (size_t)d * NROW + i0 + io) = o;
  }
}

// ---------------- fused: out = rownorm(exp(adj)) @ h ----------------
// R8 skeleton (246.8us best) with B staging moved to global_load_lds DMA +
// counted vmcnt (T4): per iter --
//   (b) exp/pack A(it) [regs from it-1] -> abuf[cur]           (1 ds_write)
//   (c) issue A global prefetch (it+1)                          (2 loads)
//   (d) lgkmcnt(0); s_waitcnt vmcnt(2)  [DMA(it) done, A(it+1) in flight]
//       s_barrier
//   (e) issue DMA B(it+2)->bbuf[cur^1] (safe: prior readers drained at (d));
//       ds_read A/B frags of tile it; MFMA (+ones rowsum)
// B's reg round-trip (4 loads + 4 ds_writes/thread) is gone; lgkmcnt drain
// before barrier covers only A's single ds_write. vmcnt never drains to 0.
__global__ __launch_bounds__(256, 2) void fused(const float* __restrict__ adj,
                                                const unsigned short* __restrict__ ht,
                                                float* __restrict__ out) {
  __shared__ __align__(16) char smem[40960];  // A: 2*4KB @0, BT: 2*16KB @8192
  const int t = threadIdx.x;
  const size_t m0 = (size_t)blockIdx.x * 32;

  // --- staging indices (pre-swizzled source chunk) ---
  const int srow = t >> 3;                         // 0..31
  const int chk = (t & 7) ^ (srow & 7);            // semantic 8-elem chunk
  const float* ap = adj + (m0 + srow) * (size_t)NROW + chk * 8;
  const unsigned short* hp = ht + (size_t)srow * NROW + chk * 8;

  // --- mfma indices ---
  const int l = t & 63, w = t >> 6;
  const int wr = w >> 1, wc = w & 1;
  const int lr = l & 15, kg = l >> 4;              // kg: k-group 0..3
  const int arow = wr * 16 + lr;                   // 0..31
  const int aoff0 = arow * 128 + (((kg    ) ^ (arow & 7)) << 4);
  const int aoff1 = arow * 128 + (((kg + 4) ^ (arow & 7)) << 4);
  const int d0 = wc * 64 + lr;                     // d&7 == lr&7 for all cf
  const int boff0 = d0 * 128 + (((kg    ) ^ (lr & 7)) << 4);
  const int boff1 = d0 * 128 + (((kg + 4) ^ (lr & 7)) << 4);

  // DMA dest base for this wave (wave-uniform; HW adds lane*16):
  // matches R8's staged layout byte-for-byte: j*4096 + w*1024 + l*16.
  const int dmaw = w * 1024;

  f32x4 acc[4];
#pragma unroll
  for (int cf = 0; cf < 4; ++cf) acc[cf] = (f32x4){0.f, 0.f, 0.f, 0.f};
  f32x4 rsum = (f32x4){0.f, 0.f, 0.f, 0.f};  // rowsum via ones-column MFMA

  f16x8 ones;
#pragma unroll
  for (int e = 0; e < 8; ++e) ones[e] = (_Float16)1.0f;

  // ---- prologue ----
  // DMA B(0) -> bbuf0 (completes under vmcnt(2) at iter 0's rendezvous)
#pragma unroll
  for (int j = 0; j < 4; ++j)
    gll16(hp + j * 32 * NROW, smem + 8192 + j * 4096 + dmaw);
  // A(0) prefetch
  float4 pa0 = *(const float4*)(ap);
  float4 pa1 = *(const float4*)(ap + 4);

  for (int it = 0; it < NITER; ++it) {
    const int cur = it & 1;

    // (b) exp + pkrtz pack + A LDS write (abuf[cur])
    const float4 a0 = pa0, a1 = pa1;
    uint4 aw;
    aw.x = pkrtz(__expf(a0.x), __expf(a0.y));
    aw.y = pkrtz(__expf(a0.z), __expf(a0.w));
    aw.z = pkrtz(__expf(a1.x), __expf(a1.y));
    aw.w = pkrtz(__expf(a1.z), __expf(a1.w));
    *(uint4*)(smem + cur * 4096 + t * 16) = aw;

    // (c) A global prefetch for it+1
    if (it + 1 < NITER) {
      const float* a = ap + (it + 1) * 64;
      pa0 = *(const float4*)(a);
      pa1 = *(const float4*)(a + 4);
    }

    // (d) rendezvous: A ds_write drained; DMA(it) forced complete while the
    // 2 newest VMEM ops (A prefetch) stay in flight. Never vmcnt(0).
    asm volatile("s_waitcnt lgkmcnt(0)" ::: "memory");
    asm volatile("s_waitcnt vmcnt(2)" ::: "memory");
    __builtin_amdgcn_s_barrier();
    asm volatile("" ::: "memory");

    // (e) issue DMA B(it+1) into the other buffer (prior readers of that
    // buffer drained their ds_reads at (d)); then fragments + MFMA.
    if (it + 1 < NITER) {
      const unsigned short* hb = hp + (it + 1) * 64;
      char* dst = smem + 8192 + (cur ^ 1) * 16384 + dmaw;
#pragma unroll
      for (int j = 0; j < 4; ++j)
        gll16(hb + j * 32 * NROW, dst + j * 4096);
    }

    const char* aB = smem + cur * 4096;
    const char* bB = smem + 8192 + cur * 16384;
    __builtin_amdgcn_s_setprio(1);
    f16x8 af0 = *(const f16x8*)(aB + aoff0);
    f16x8 af1 = *(const f16x8*)(aB + aoff1);
    rsum = __builtin_amdgcn_mfma_f32_16x16x32_f16(af0, ones, rsum, 0, 0, 0);
#pragma unroll
    for (int cf = 0; cf < 4; ++cf) {
      f16x8 bf0 = *(const f16x8*)(bB + boff0 + cf * 2048);
      acc[cf] = __builtin_amdgcn_mfma_f32_16x16x32_f16(af0, bf0, acc[cf], 0, 0, 0);
    }
    rsum = __builtin_amdgcn_mfma_f32_16x16x32_f16(af1, ones, rsum, 0, 0, 0);
#pragma unroll
    for (int cf = 0; cf < 4; ++cf) {
      f16x8 bf1 = *(const f16x8*)(bB + boff1 + cf * 2048);
      acc[cf] = __builtin_amdgcn_mfma_f32_16x16x32_f16(af1, bf1, acc[cf], 0, 0, 0);
    }
    __builtin_amdgcn_s_setprio(0);
  }

  // epilogue: D[(kg*4+r)][lr]; rsum[r] holds this lane's row's sum
#pragma unroll
  for (int r = 0; r < 4; ++r) {
    const int row_l = wr * 16 + kg * 4 + r;
    const float inv = 1.0f / rsum[r];
    float* orow = out + (m0 + row_l) * (size_t)DDIM + wc * 64 + lr;
#pragma unroll
    for (int cf = 0; cf < 4; ++cf) {
      orow[cf * 16] = acc[cf][r] * inv;
    }
  }
}

extern "C" void kernel_launch(void* const* d_in, const int* in_sizes, int n_in,
                              void* d_out, int out_size, void* d_ws, size_t ws_size,
                              hipStream_t stream) {
  (void)in_sizes; (void)n_in; (void)out_size; (void)ws_size;
  const float* h   = (const float*)d_in[0];
  const float* adj = (const float*)d_in[1];
  float* out = (float*)d_out;
  unsigned short* ht = (unsigned short*)d_ws;  // 128*16384 fp16 = 4 MB

  prep_ht<<<dim3(NROW / 64), dim3(256), 0, stream>>>(h, ht);
  fused<<<dim3(NROW / 32), dim3(256), 0, stream>>>(adj, ht, out);
}